// Round 13
// baseline (639.185 us; speedup 1.0000x reference)
//
#include <hip/hip_runtime.h>
#include <float.h>

#define NQ      4096
#define NKEYS   65536
#define DKDIM   128
#define DVDIM   128
#define TOPK_N  32
#define NSPLIT  32
#define KPS     (NKEYS / NSPLIT)        // 2048 keys per split (li fits 12 bits)
#define BQ      128                     // queries per block (8 waves x 16)
#define NCAND   (NSPLIT * TOPK_N)       // 1024 candidates per query
#define NARROW  64                      // exact-rescore width in kernel C
#define NOUT    ((size_t)NQ * TOPK_N * DKDIM)
#define KPT     64                      // keys per staged LDS tile
#define NT      (KPS / KPT)             // 32 tiles per split

typedef __attribute__((ext_vector_type(8))) short short8;   // 8 bf16
typedef __attribute__((ext_vector_type(4))) float v4f;      // MFMA acc

__device__ inline unsigned short f2bf(float f) {            // RNE fp32->bf16
    unsigned int u = __float_as_uint(f);
    return (unsigned short)((u + 0x7FFFu + ((u >> 16) & 1u)) >> 16);
}

// Packed candidate: (monotone-folded fp32 score, top 20 bits) | (4095 - li).
// Unsigned-descending order == (score desc, tie -> lower li).  0 == empty pad.
__device__ inline unsigned packpk(float s, unsigned li) {
    unsigned u = __float_as_uint(s);
    u = ((int)u < 0) ? ~u : (u | 0x80000000u);
    return (u & 0xFFFFF000u) | (4095u - li);
}
// Lower bound of the score encoded in pk (truncation rounds toward -inf).
__device__ inline float unpack_lb(unsigned pk) {
    const unsigned m = pk & 0xFFFFF000u;
    const unsigned b = (m & 0x80000000u) ? (m & 0x7FFFFFFFu) : ~m;
    return __uint_as_float(b);
}

// Cross-lane compare-exchange on one packed word (within 16-lane quad; s<16).
#define CEXU(p, s, desc) {                                                  \
    const unsigned _o = (unsigned)__shfl_xor((int)(p), (s));                \
    const bool _first = (p) > _o;                                           \
    const bool _keep  = (_first == (((l16 & (s)) == 0) == (desc)));         \
    (p) = _keep ? (p) : _o; }
// Intra-lane: keep larger in a (descending position).
#define CEXUI(pa, pb) { if ((pb) > (pa)) { const unsigned _t=(pa); (pa)=(pb); (pb)=_t; } }

// Compact one query's append region (<=32 packed words in LDS) into the
// register-resident sorted pool (p0/p1 desc over slots l16, 16+l16).
// Bitonic sort-32 + bitonic split + p-side cleanup (c-side discarded).
__device__ __forceinline__ void sortmergeU(
    unsigned& p0, unsigned& p1, const int cc,
    const unsigned* __restrict__ bqr, const int l16)
{
    unsigned s0 = (l16      < cc) ? bqr[l16]      : 0u;
    unsigned s1 = (l16 + 16 < cc) ? bqr[l16 + 16] : 0u;

    // Bitonic sort-32, descending (mirrored: desc = ((a&k)==0)).
    CEXU(s0, 1, ((l16 & 2) == 0)); CEXU(s1, 1, ((l16 & 2) == 0));   // k=2
    CEXU(s0, 2, ((l16 & 4) == 0)); CEXU(s1, 2, ((l16 & 4) == 0));   // k=4
    CEXU(s0, 1, ((l16 & 4) == 0)); CEXU(s1, 1, ((l16 & 4) == 0));
    CEXU(s0, 4, ((l16 & 8) == 0)); CEXU(s1, 4, ((l16 & 8) == 0));   // k=8
    CEXU(s0, 2, ((l16 & 8) == 0)); CEXU(s1, 2, ((l16 & 8) == 0));
    CEXU(s0, 1, ((l16 & 8) == 0)); CEXU(s1, 1, ((l16 & 8) == 0));
    CEXU(s0, 8, true);  CEXU(s1, 8, false);                         // k=16
    CEXU(s0, 4, true);  CEXU(s1, 4, false);
    CEXU(s0, 2, true);  CEXU(s1, 2, false);
    CEXU(s0, 1, true);  CEXU(s1, 1, false);
    CEXUI(s0, s1);                                                  // k=32 s=16
    CEXU(s0, 8, true);  CEXU(s1, 8, true);
    CEXU(s0, 4, true);  CEXU(s1, 4, true);
    CEXU(s0, 2, true);  CEXU(s1, 2, true);
    CEXU(s0, 1, true);  CEXU(s1, 1, true);

    // Reverse (desc -> asc): bitonic 64-seq {p0,p1,c0,c1}.
    unsigned c0 = (unsigned)__shfl_xor((int)s1, 15);
    unsigned c1 = (unsigned)__shfl_xor((int)s0, 15);

    // s=32: bitonic split -- after this, {p0,p1} hold the top-32 set.
    CEXUI(p0, c0);
    CEXUI(p1, c1);
    // p-side cleanup only.
    CEXUI(p0, p1);                     // s=16
    CEXU(p0, 8, true); CEXU(p1, 8, true);
    CEXU(p0, 4, true); CEXU(p1, 4, true);
    CEXU(p0, 2, true); CEXU(p1, 2, true);
    CEXU(p0, 1, true); CEXU(p1, 1, true);
}

// ---------------------------------------------------------------------------
// Kernel A: convert q and keys to bf16 (workspace).
// ---------------------------------------------------------------------------
__global__ __launch_bounds__(256) void convert_kernel(
    const float* __restrict__ q, const float* __restrict__ keys,
    unsigned short* __restrict__ qbf, unsigned short* __restrict__ kbf)
{
    const size_t QG = (size_t)NQ * DKDIM / 8;       // 65536 groups of 8
    const size_t KG = (size_t)NKEYS * DKDIM / 8;    // 1048576
    const size_t g  = (size_t)blockIdx.x * 256 + threadIdx.x;
    if (g >= QG + KG) return;
    const float* src;
    unsigned short* dst;
    if (g < QG) { src = q + g * 8;         dst = qbf + g * 8; }
    else        { const size_t h = g - QG; src = keys + h * 8; dst = kbf + h * 8; }
    const float4 a = ((const float4*)src)[0];
    const float4 b = ((const float4*)src)[1];
    short8 o;
    o[0] = (short)f2bf(a.x); o[1] = (short)f2bf(a.y);
    o[2] = (short)f2bf(a.z); o[3] = (short)f2bf(a.w);
    o[4] = (short)f2bf(b.x); o[5] = (short)f2bf(b.y);
    o[6] = (short)f2bf(b.z); o[7] = (short)f2bf(b.w);
    *(short8*)dst = o;
}

// ---------------------------------------------------------------------------
// Kernel B: transposed-MFMA bf16 approx scores + per-(query,split) top-32 as
// PACKED 32-bit candidates.  Round-12-proven structure (BQ=128, KPT=64,
// 8-wave blocks, double-buffered staging, one barrier per 64-key tile).
// ROUND 13: NSPLIT 16 -> 32 so grid = 1024 blocks -> 3 blocks/CU resident
// (LDS-capped: 3 x 48.5 KB <= 160 KB) = 24 waves/CU, up from 16.
// XCD remap: lin = 8*rest + c; split = 4c + (rest&3), qgrp = rest>>2 ->
// XCD c touches only splits {4c..4c+3} (4 x 512 KB = 2 MB, L2-resident).
// MFMA 16x16x32 with A=K-tile, B=Q-tile -> D is S^T:
//   lane l, reg r -> S[key n0 + (l>>4)*4 + r][query q0 + (l&15)].
// ---------------------------------------------------------------------------
__global__ __launch_bounds__(512, 4) void score_select_kernel(
    const unsigned short* __restrict__ qbf, const unsigned short* __restrict__ kbf,
    unsigned* __restrict__ cand)
{
    __shared__ unsigned short kst[2][KPT * DKDIM];   // 2 x 16 KB staged K tiles
    __shared__ unsigned bq[BQ][33];                  // 16.9 KB packed appends

    const int tid  = threadIdx.x;
    const int wave = tid >> 6;      // 0..7
    const int lane = tid & 63;
    const int l16  = lane & 15;
    const int quad = lane >> 4;

    const int lin   = blockIdx.y * gridDim.x + blockIdx.x;   // [0, 1024)
    const int rest  = lin >> 3;                              // [0, 128)
    const int split = ((lin & 7) << 2) | (rest & 3);         // [0, 32)
    const int qgrp  = rest >> 2;                             // [0, 32)
    const int q0    = qgrp * BQ + wave * 16;
    const int nbase = split * KPS;

    unsigned* __restrict__ bqr = &bq[wave * 16 + l16][0];   // lane's query row

    // Q fragments (B-operand): lane holds Q[q0+l16][quad*8 + 32t + j].
    short8 afrag[4];
#pragma unroll
    for (int t = 0; t < 4; ++t)
        afrag[t] = *(const short8*)(qbf + (size_t)(q0 + l16) * DKDIM + t * 32 + quad * 8);

    // Pool (quad-orientation: query quad*4+r, sorted desc over l16, 16+l16).
    unsigned pk0[4], pk1[4];
#pragma unroll
    for (int r = 0; r < 4; ++r) { pk0[r] = 0u; pk1[r] = 0u; }
    float vmf = -FLT_MAX;     // lane-orientation threshold (query l16)
    int   cnt = 0;

    auto select32 = [&](const v4f a1, const v4f a2, const int n0loc) {
        const int h0 = a1[0] > vmf, h1 = a1[1] > vmf, h2 = a1[2] > vmf, h3 = a1[3] > vmf;
        const int h4 = a2[0] > vmf, h5 = a2[1] > vmf, h6 = a2[2] > vmf, h7 = a2[3] > vmf;
        const int nh = h0 + h1 + h2 + h3 + h4 + h5 + h6 + h7;
        const int s16   = __shfl_xor(nh, 16);
        const int psum  = nh + s16;
        const int sx32  = __shfl_xor(psum, 32);
        const int nhcol = psum + sx32;
        if (__ballot(cnt + nhcol > 32)) {            // wave-uniform compaction
#pragma unroll
            for (int r = 0; r < 4; ++r) {
                const int cc = __shfl(cnt, quad * 4 + r);
                sortmergeU(pk0[r], pk1[r], cc, &bq[wave * 16 + quad * 4 + r][0], l16);
            }
            // Pool-min (slot 31 = pk1 at l16==15 of owner quad) -> lane-orient.
            const unsigned t0 = (unsigned)__shfl((int)pk1[0], (l16 >> 2) * 16 + 15);
            const unsigned t1 = (unsigned)__shfl((int)pk1[1], (l16 >> 2) * 16 + 15);
            const unsigned t2 = (unsigned)__shfl((int)pk1[2], (l16 >> 2) * 16 + 15);
            const unsigned t3 = (unsigned)__shfl((int)pk1[3], (l16 >> 2) * 16 + 15);
            const unsigned a01 = (l16 & 1) ? t1 : t0;
            const unsigned a23 = (l16 & 1) ? t3 : t2;
            vmf = unpack_lb((l16 & 2) ? a23 : a01);
            cnt = 0;
        }
        int pos = cnt + ((quad & 1) ? s16 : 0) + ((quad & 2) ? sx32 : 0);
        const unsigned lb = (unsigned)(n0loc + quad * 4);
        if (h0) { bqr[pos] = packpk(a1[0], lb);      ++pos; }
        if (h1) { bqr[pos] = packpk(a1[1], lb + 1);  ++pos; }
        if (h2) { bqr[pos] = packpk(a1[2], lb + 2);  ++pos; }
        if (h3) { bqr[pos] = packpk(a1[3], lb + 3);  ++pos; }
        if (h4) { bqr[pos] = packpk(a2[0], lb + 16); ++pos; }
        if (h5) { bqr[pos] = packpk(a2[1], lb + 17); ++pos; }
        if (h6) { bqr[pos] = packpk(a2[2], lb + 18); ++pos; }
        if (h7) { bqr[pos] = packpk(a2[3], lb + 19); }
        cnt += nhcol;
    };

    // ---- Staging: tile = 64 rows x 256 B = 1024 16B-chunks; thread stages
    // chunks c0=tid, c1=tid+512.  Chunk-XOR swizzle (involution, row-local).
    const unsigned short* ksrc = kbf + (size_t)nbase * DKDIM;
    const int c0 = tid, c1 = tid + 512;
    const int d0 = ((c0 >> 4) * 128) + (((c0 & 15) ^ ((c0 >> 4) & 7)) * 8);
    const int d1 = ((c1 >> 4) * 128) + (((c1 & 15) ^ ((c1 >> 4) & 7)) * 8);
    const int sx = l16 & 7;     // read-side swizzle: tile rows == l16 (mod 8)

    {   // Prologue: stage tile 0.
        const short8 a = *(const short8*)(ksrc + c0 * 8);
        const short8 b = *(const short8*)(ksrc + c1 * 8);
        *(short8*)&kst[0][d0] = a;
        *(short8*)&kst[0][d1] = b;
    }
    __syncthreads();

    int cur = 0;
    for (int t = 0; t < NT; ++t) {
        short8 nA, nB;
        const bool more = (t + 1 < NT);
        if (more) {   // issue next tile's loads early (hide under compute)
            const unsigned short* s = ksrc + (size_t)(t + 1) * (KPT * DKDIM);
            nA = *(const short8*)(s + c0 * 8);
            nB = *(const short8*)(s + c1 * 8);
        }
        // Two select32 passes over the 64-key tile (rows 0..31, then 32..63).
#pragma unroll
        for (int half = 0; half < 2; ++half) {
            const unsigned short* kr0 = &kst[cur][(half * 32 + l16) * 128];
            const unsigned short* kr1 = &kst[cur][(half * 32 + 16 + l16) * 128];
            v4f acc1 = {0.f, 0.f, 0.f, 0.f};
            v4f acc2 = {0.f, 0.f, 0.f, 0.f};
#pragma unroll
            for (int tt = 0; tt < 4; ++tt) {
                const short8 b0 = *(const short8*)(kr0 + ((quad + tt * 4) ^ sx) * 8);
                const short8 b1 = *(const short8*)(kr1 + ((quad + tt * 4) ^ sx) * 8);
                acc1 = __builtin_amdgcn_mfma_f32_16x16x32_bf16(b0, afrag[tt], acc1, 0, 0, 0);
                acc2 = __builtin_amdgcn_mfma_f32_16x16x32_bf16(b1, afrag[tt], acc2, 0, 0, 0);
            }
            select32(acc1, acc2, t * KPT + half * 32);
        }
        if (more) {
            *(short8*)&kst[cur ^ 1][d0] = nA;
            *(short8*)&kst[cur ^ 1][d1] = nB;
        }
        __syncthreads();
        cur ^= 1;
    }

    // Final flush + writeout (quad-orientation; pool sorted desc).
#pragma unroll
    for (int r = 0; r < 4; ++r) {
        const int cc = __shfl(cnt, quad * 4 + r);
        sortmergeU(pk0[r], pk1[r], cc, &bq[wave * 16 + quad * 4 + r][0], l16);
        const size_t base = ((size_t)(q0 + quad * 4 + r) * NSPLIT + split) * TOPK_N;
        cand[base + l16]      = pk0[r];
        cand[base + 16 + l16] = pk1[r];
    }
}

// ---------------------------------------------------------------------------
// Kernel C: narrow-then-rescore, NCAND=1024.  Hybrid bitonic sort-1024 with
// TWO elements per thread (e0 = tid, e1 = tid+512): for j < 512 both
// elements' partners live on thread tid^j (shfl if j<64, LDS if 64<=j<512);
// j==512 is an intra-thread compare.  dir computed per element from e&k.
// Same verified comparator/tie semantics (pk desc, tie -> lower n).
// fp32 rescore of top NARROW=64 via the SACRED SEQUENTIAL fmaf chain
// (bitwise-matches np reference; do NOT reassociate — round-9 failure).
// Margin: candidate 32nd->64th approx gap ~1.5 >> bf16+trunc error ~0.11.
// Final exact sort-64 is pure intra-wave shfl (wave 0, zero barriers).
// One block (512 threads) per query.
// ---------------------------------------------------------------------------
__global__ __launch_bounds__(512) void rescore_gather_kernel(
    const float* __restrict__ qg, const float* __restrict__ keys,
    const float* __restrict__ values, const unsigned* __restrict__ cand,
    float* __restrict__ out)
{
    __shared__ float    qrow[DKDIM];
    __shared__ unsigned spk[NCAND];
    __shared__ int      spn[NCAND];
    __shared__ int      ssi[TOPK_N];
    const int bt  = blockIdx.x;
    const int tid = threadIdx.x;

    if (tid < DKDIM) qrow[tid] = qg[(size_t)bt * DKDIM + tid];

    // Load both elements (coalesced).
    unsigned pkA = cand[(size_t)bt * NCAND + tid];
    unsigned pkB = cand[(size_t)bt * NCAND + tid + 512];
    int nA = (tid >> 5) * KPS + (int)(4095u - (pkA & 0xFFFu));
    int nB = ((tid + 512) >> 5) * KPS + (int)(4095u - (pkB & 0xFFFu));

    // Hybrid bitonic sort-1024, descending by pk (tie -> lower n).
    for (int k = 2; k <= NCAND; k <<= 1) {
        for (int j = k >> 1; j > 0; j >>= 1) {
            if (j == 512) {         // k==1024 only: e0 <-> e1, both dir desc
                const bool bFirst = (pkB > pkA) || (pkB == pkA && nB < nA);
                if (bFirst) {
                    const unsigned tp = pkA; pkA = pkB; pkB = tp;
                    const int      tn = nA;  nA  = nB;  nB  = tn;
                }
                continue;
            }
            unsigned oA, oB; int mA, mB;
            if (j >= 64) {                      // cross-wave: via LDS
                __syncthreads();
                spk[tid] = pkA; spn[tid] = nA;
                spk[tid + 512] = pkB; spn[tid + 512] = nB;
                __syncthreads();
                oA = spk[tid ^ j];           mA = spn[tid ^ j];
                oB = spk[(tid ^ j) + 512];   mB = spn[(tid ^ j) + 512];
            } else {                            // intra-wave: register shfl
                oA = (unsigned)__shfl_xor((int)pkA, j); mA = __shfl_xor(nA, j);
                oB = (unsigned)__shfl_xor((int)pkB, j); mB = __shfl_xor(nB, j);
            }
            const bool dirA = ((tid & k) == 0);
            const bool dirB = (((tid + 512) & k) == 0);
            const bool upper = ((tid & j) == 0);    // same for e0 and e1 (j<512)
            const bool fA = (pkA > oA) || (pkA == oA && nA < mA);
            const bool fB = (pkB > oB) || (pkB == oB && nB < mB);
            if (!(upper == (fA == dirA))) { pkA = oA; nA = mA; }
            if (!(upper == (fB == dirB))) { pkB = oB; nB = mB; }
        }
    }
    __syncthreads();    // qrow visible; sort done.  Rank tid element = (pkA,nA).

    // Exact fp32 rescore of ranks 0..NARROW-1: sequential fmaf over d=0..127.
    float sc = -FLT_MAX;
    int   n  = nA;
    if (tid < NARROW) {
        const float4* krow = (const float4*)(keys + (size_t)n * DKDIM);
        float s = 0.f;
#pragma unroll
        for (int d4 = 0; d4 < DKDIM / 4; ++d4) {
            const float4 k4 = krow[d4];
            const float4 q4 = *(const float4*)&qrow[4 * d4];
            s = fmaf(q4.x, k4.x, s);
            s = fmaf(q4.y, k4.y, s);
            s = fmaf(q4.z, k4.z, s);
            s = fmaf(q4.w, k4.w, s);
        }
        sc = s;
    }

    // Exact bitonic sort-64 (desc, tie -> lower idx): entirely within wave 0
    // (threads 0..63), pure shfl, zero barriers.
    if (tid < 64) {
        for (int k = 2; k <= NARROW; k <<= 1) {
            for (int j = k >> 1; j > 0; j >>= 1) {
                const float of = __shfl_xor(sc, j);
                const int   on = __shfl_xor(n, j);
                const bool dir  = ((tid & k) == 0);
                const bool mineFirst = (sc > of) || (sc == of && n < on);
                const bool keep = (((tid & j) == 0) == (mineFirst == dir));
                if (!keep) { sc = of; n = on; }
            }
        }
        if (tid < TOPK_N) ssi[tid] = n;
    }
    __syncthreads();

    // Gather top-32 K and V rows.
    const int lane = tid & 31;
    const int rb   = tid >> 5;          // [0, 16)
#pragma unroll
    for (int r = 0; r < 2; ++r) {
        const int row = rb + 16 * r;
        const int nn  = ssi[row];
        const float4 kv = *(const float4*)(keys   + (size_t)nn * DKDIM + 4 * lane);
        const float4 vv = *(const float4*)(values + (size_t)nn * DVDIM + 4 * lane);
        const size_t ob = ((size_t)bt * TOPK_N + row) * DKDIM + 4 * lane;
        *(float4*)(out + ob)        = kv;
        *(float4*)(out + NOUT + ob) = vv;
    }
}

extern "C" void kernel_launch(void* const* d_in, const int* in_sizes, int n_in,
                              void* d_out, int out_size, void* d_ws, size_t ws_size,
                              hipStream_t stream)
{
    const float* q      = (const float*)d_in[0];
    const float* keys   = (const float*)d_in[1];
    const float* values = (const float*)d_in[2];
    float* out = (float*)d_out;

    unsigned short* qbf = (unsigned short*)d_ws;                               // 1 MB
    unsigned short* kbf = (unsigned short*)((char*)d_ws + (1u << 20));         // 16 MB
    unsigned* cand = (unsigned*)((char*)d_ws + (17u << 20));                   // 16 MB

    const int cvt_groups = (NQ + NKEYS) * DKDIM / 8;
    convert_kernel<<<(cvt_groups + 255) / 256, 256, 0, stream>>>(q, keys, qbf, kbf);
    score_select_kernel<<<dim3(NQ / BQ, NSPLIT), 512, 0, stream>>>(qbf, kbf, cand);
    rescore_gather_kernel<<<NQ, 512, 0, stream>>>(q, keys, values, cand, out);
}

// Round 14
// 533.622 us; speedup vs baseline: 1.1978x; 1.1978x over previous
//
#include <hip/hip_runtime.h>
#include <float.h>

#define NQ      4096
#define NKEYS   65536
#define DKDIM   128
#define DVDIM   128
#define TOPK_N  32
#define NSPLIT  16
#define KPS     (NKEYS / NSPLIT)        // 4096 keys per split (li fits 12 bits)
#define BQ      128                     // queries per block (8 waves x 16)
#define NCAND   (NSPLIT * TOPK_N)       // 512 candidates per query
#define NARROW  64                      // exact-rescore width in kernel C
#define NOUT    ((size_t)NQ * TOPK_N * DKDIM)
#define KPT     64                      // keys per staged LDS tile
#define NT      (KPS / KPT)             // 64 tiles per split

typedef __attribute__((ext_vector_type(8))) short short8;   // 8 bf16
typedef __attribute__((ext_vector_type(4))) float v4f;      // MFMA acc

__device__ inline unsigned short f2bf(float f) {            // RNE fp32->bf16
    unsigned int u = __float_as_uint(f);
    return (unsigned short)((u + 0x7FFFu + ((u >> 16) & 1u)) >> 16);
}

// Packed candidate: (monotone-folded fp32 score, top 20 bits) | (4095 - li).
// Unsigned-descending order == (score desc, tie -> lower li).  0 == empty pad.
__device__ inline unsigned packpk(float s, unsigned li) {
    unsigned u = __float_as_uint(s);
    u = ((int)u < 0) ? ~u : (u | 0x80000000u);
    return (u & 0xFFFFF000u) | (4095u - li);
}
// Lower bound of the score encoded in pk (truncation rounds toward -inf).
__device__ inline float unpack_lb(unsigned pk) {
    const unsigned m = pk & 0xFFFFF000u;
    const unsigned b = (m & 0x80000000u) ? (m & 0x7FFFFFFFu) : ~m;
    return __uint_as_float(b);
}

// Cross-lane compare-exchange on one packed word (within 16-lane quad; s<16).
#define CEXU(p, s, desc) {                                                  \
    const unsigned _o = (unsigned)__shfl_xor((int)(p), (s));                \
    const bool _first = (p) > _o;                                           \
    const bool _keep  = (_first == (((l16 & (s)) == 0) == (desc)));         \
    (p) = _keep ? (p) : _o; }
// Intra-lane: keep larger in a (descending position).
#define CEXUI(pa, pb) { if ((pb) > (pa)) { const unsigned _t=(pa); (pa)=(pb); (pb)=_t; } }

// Compact one query's append region (<=32 packed words in LDS) into the
// register-resident sorted pool (p0/p1 desc over slots l16, 16+l16).
// Bitonic sort-32 + bitonic split + p-side cleanup (c-side discarded).
__device__ __forceinline__ void sortmergeU(
    unsigned& p0, unsigned& p1, const int cc,
    const unsigned* __restrict__ bqr, const int l16)
{
    unsigned s0 = (l16      < cc) ? bqr[l16]      : 0u;
    unsigned s1 = (l16 + 16 < cc) ? bqr[l16 + 16] : 0u;

    // Bitonic sort-32, descending (mirrored: desc = ((a&k)==0)).
    CEXU(s0, 1, ((l16 & 2) == 0)); CEXU(s1, 1, ((l16 & 2) == 0));   // k=2
    CEXU(s0, 2, ((l16 & 4) == 0)); CEXU(s1, 2, ((l16 & 4) == 0));   // k=4
    CEXU(s0, 1, ((l16 & 4) == 0)); CEXU(s1, 1, ((l16 & 4) == 0));
    CEXU(s0, 4, ((l16 & 8) == 0)); CEXU(s1, 4, ((l16 & 8) == 0));   // k=8
    CEXU(s0, 2, ((l16 & 8) == 0)); CEXU(s1, 2, ((l16 & 8) == 0));
    CEXU(s0, 1, ((l16 & 8) == 0)); CEXU(s1, 1, ((l16 & 8) == 0));
    CEXU(s0, 8, true);  CEXU(s1, 8, false);                         // k=16
    CEXU(s0, 4, true);  CEXU(s1, 4, false);
    CEXU(s0, 2, true);  CEXU(s1, 2, false);
    CEXU(s0, 1, true);  CEXU(s1, 1, false);
    CEXUI(s0, s1);                                                  // k=32 s=16
    CEXU(s0, 8, true);  CEXU(s1, 8, true);
    CEXU(s0, 4, true);  CEXU(s1, 4, true);
    CEXU(s0, 2, true);  CEXU(s1, 2, true);
    CEXU(s0, 1, true);  CEXU(s1, 1, true);

    // Reverse (desc -> asc): bitonic 64-seq {p0,p1,c0,c1}.
    unsigned c0 = (unsigned)__shfl_xor((int)s1, 15);
    unsigned c1 = (unsigned)__shfl_xor((int)s0, 15);

    // s=32: bitonic split -- after this, {p0,p1} hold the top-32 set.
    CEXUI(p0, c0);
    CEXUI(p1, c1);
    // p-side cleanup only.
    CEXUI(p0, p1);                     // s=16
    CEXU(p0, 8, true); CEXU(p1, 8, true);
    CEXU(p0, 4, true); CEXU(p1, 4, true);
    CEXU(p0, 2, true); CEXU(p1, 2, true);
    CEXU(p0, 1, true); CEXU(p1, 1, true);
}

// ---------------------------------------------------------------------------
// Kernel A: convert q and keys to bf16 (workspace).
// ---------------------------------------------------------------------------
__global__ __launch_bounds__(256) void convert_kernel(
    const float* __restrict__ q, const float* __restrict__ keys,
    unsigned short* __restrict__ qbf, unsigned short* __restrict__ kbf)
{
    const size_t QG = (size_t)NQ * DKDIM / 8;       // 65536 groups of 8
    const size_t KG = (size_t)NKEYS * DKDIM / 8;    // 1048576
    const size_t g  = (size_t)blockIdx.x * 256 + threadIdx.x;
    if (g >= QG + KG) return;
    const float* src;
    unsigned short* dst;
    if (g < QG) { src = q + g * 8;         dst = qbf + g * 8; }
    else        { const size_t h = g - QG; src = keys + h * 8; dst = kbf + h * 8; }
    const float4 a = ((const float4*)src)[0];
    const float4 b = ((const float4*)src)[1];
    short8 o;
    o[0] = (short)f2bf(a.x); o[1] = (short)f2bf(a.y);
    o[2] = (short)f2bf(a.z); o[3] = (short)f2bf(a.w);
    o[4] = (short)f2bf(b.x); o[5] = (short)f2bf(b.y);
    o[6] = (short)f2bf(b.z); o[7] = (short)f2bf(b.w);
    *(short8*)dst = o;
}

// ---------------------------------------------------------------------------
// Kernel B: transposed-MFMA bf16 approx scores + per-(query,split) top-32 as
// PACKED 32-bit candidates.  ROUND 14: byte-identical revert to the round-12
// configuration (measured 320 us) — BQ=128, KPT=64, NSPLIT=16, 8-wave
// blocks, double-buffered staging, one barrier per 64-key tile.  (Round 13's
// NSPLIT=32 regressed: residency stayed 2 blocks/CU while insert work grew.)
// Grid (NQ/BQ=32, NSPLIT=16) = 512 blocks; XCD-aware bijective remap.
// MFMA 16x16x32 with A=K-tile, B=Q-tile -> D is S^T:
//   lane l, reg r -> S[key n0 + (l>>4)*4 + r][query q0 + (l&15)].
// ---------------------------------------------------------------------------
__global__ __launch_bounds__(512, 4) void score_select_kernel(
    const unsigned short* __restrict__ qbf, const unsigned short* __restrict__ kbf,
    unsigned* __restrict__ cand)
{
    __shared__ unsigned short kst[2][KPT * DKDIM];   // 2 x 16 KB staged K tiles
    __shared__ unsigned bq[BQ][33];                  // 16.9 KB packed appends

    const int tid  = threadIdx.x;
    const int wave = tid >> 6;      // 0..7
    const int lane = tid & 63;
    const int l16  = lane & 15;
    const int quad = lane >> 4;

    // XCD-aware remap (bijective): lin = 256*a + 8*b + c, lin in [0,512);
    // split = 2c + a, qgrp = b.  Blocks with lin%8 == c land on XCD c and
    // touch only splits {2c, 2c+1} (2 MB kbf slice, L2-resident).
    const int lin   = blockIdx.y * gridDim.x + blockIdx.x;   // [0, 512)
    const int split = ((lin & 7) << 1) | (lin >> 8);
    const int qgrp  = (lin >> 3) & 31;
    const int q0    = qgrp * BQ + wave * 16;
    const int nbase = split * KPS;

    unsigned* __restrict__ bqr = &bq[wave * 16 + l16][0];   // lane's query row

    // Q fragments (B-operand): lane holds Q[q0+l16][quad*8 + 32t + j].
    short8 afrag[4];
#pragma unroll
    for (int t = 0; t < 4; ++t)
        afrag[t] = *(const short8*)(qbf + (size_t)(q0 + l16) * DKDIM + t * 32 + quad * 8);

    // Pool (quad-orientation: query quad*4+r, sorted desc over l16, 16+l16).
    unsigned pk0[4], pk1[4];
#pragma unroll
    for (int r = 0; r < 4; ++r) { pk0[r] = 0u; pk1[r] = 0u; }
    float vmf = -FLT_MAX;     // lane-orientation threshold (query l16)
    int   cnt = 0;

    auto select32 = [&](const v4f a1, const v4f a2, const int n0loc) {
        const int h0 = a1[0] > vmf, h1 = a1[1] > vmf, h2 = a1[2] > vmf, h3 = a1[3] > vmf;
        const int h4 = a2[0] > vmf, h5 = a2[1] > vmf, h6 = a2[2] > vmf, h7 = a2[3] > vmf;
        const int nh = h0 + h1 + h2 + h3 + h4 + h5 + h6 + h7;
        const int s16   = __shfl_xor(nh, 16);
        const int psum  = nh + s16;
        const int sx32  = __shfl_xor(psum, 32);
        const int nhcol = psum + sx32;
        if (__ballot(cnt + nhcol > 32)) {            // wave-uniform compaction
#pragma unroll
            for (int r = 0; r < 4; ++r) {
                const int cc = __shfl(cnt, quad * 4 + r);
                sortmergeU(pk0[r], pk1[r], cc, &bq[wave * 16 + quad * 4 + r][0], l16);
            }
            // Pool-min (slot 31 = pk1 at l16==15 of owner quad) -> lane-orient.
            const unsigned t0 = (unsigned)__shfl((int)pk1[0], (l16 >> 2) * 16 + 15);
            const unsigned t1 = (unsigned)__shfl((int)pk1[1], (l16 >> 2) * 16 + 15);
            const unsigned t2 = (unsigned)__shfl((int)pk1[2], (l16 >> 2) * 16 + 15);
            const unsigned t3 = (unsigned)__shfl((int)pk1[3], (l16 >> 2) * 16 + 15);
            const unsigned a01 = (l16 & 1) ? t1 : t0;
            const unsigned a23 = (l16 & 1) ? t3 : t2;
            vmf = unpack_lb((l16 & 2) ? a23 : a01);
            cnt = 0;
        }
        int pos = cnt + ((quad & 1) ? s16 : 0) + ((quad & 2) ? sx32 : 0);
        const unsigned lb = (unsigned)(n0loc + quad * 4);
        if (h0) { bqr[pos] = packpk(a1[0], lb);      ++pos; }
        if (h1) { bqr[pos] = packpk(a1[1], lb + 1);  ++pos; }
        if (h2) { bqr[pos] = packpk(a1[2], lb + 2);  ++pos; }
        if (h3) { bqr[pos] = packpk(a1[3], lb + 3);  ++pos; }
        if (h4) { bqr[pos] = packpk(a2[0], lb + 16); ++pos; }
        if (h5) { bqr[pos] = packpk(a2[1], lb + 17); ++pos; }
        if (h6) { bqr[pos] = packpk(a2[2], lb + 18); ++pos; }
        if (h7) { bqr[pos] = packpk(a2[3], lb + 19); }
        cnt += nhcol;
    };

    // ---- Staging: tile = 64 rows x 256 B = 1024 16B-chunks; thread stages
    // chunks c0=tid, c1=tid+512.  Chunk-XOR swizzle (involution, row-local).
    const unsigned short* ksrc = kbf + (size_t)nbase * DKDIM;
    const int c0 = tid, c1 = tid + 512;
    const int d0 = ((c0 >> 4) * 128) + (((c0 & 15) ^ ((c0 >> 4) & 7)) * 8);
    const int d1 = ((c1 >> 4) * 128) + (((c1 & 15) ^ ((c1 >> 4) & 7)) * 8);
    const int sx = l16 & 7;     // read-side swizzle: tile rows == l16 (mod 8)

    {   // Prologue: stage tile 0.
        const short8 a = *(const short8*)(ksrc + c0 * 8);
        const short8 b = *(const short8*)(ksrc + c1 * 8);
        *(short8*)&kst[0][d0] = a;
        *(short8*)&kst[0][d1] = b;
    }
    __syncthreads();

    int cur = 0;
    for (int t = 0; t < NT; ++t) {
        short8 nA, nB;
        const bool more = (t + 1 < NT);
        if (more) {   // issue next tile's loads early (hide under compute)
            const unsigned short* s = ksrc + (size_t)(t + 1) * (KPT * DKDIM);
            nA = *(const short8*)(s + c0 * 8);
            nB = *(const short8*)(s + c1 * 8);
        }
        // Two select32 passes over the 64-key tile (rows 0..31, then 32..63).
#pragma unroll
        for (int half = 0; half < 2; ++half) {
            const unsigned short* kr0 = &kst[cur][(half * 32 + l16) * 128];
            const unsigned short* kr1 = &kst[cur][(half * 32 + 16 + l16) * 128];
            v4f acc1 = {0.f, 0.f, 0.f, 0.f};
            v4f acc2 = {0.f, 0.f, 0.f, 0.f};
#pragma unroll
            for (int tt = 0; tt < 4; ++tt) {
                const short8 b0 = *(const short8*)(kr0 + ((quad + tt * 4) ^ sx) * 8);
                const short8 b1 = *(const short8*)(kr1 + ((quad + tt * 4) ^ sx) * 8);
                acc1 = __builtin_amdgcn_mfma_f32_16x16x32_bf16(b0, afrag[tt], acc1, 0, 0, 0);
                acc2 = __builtin_amdgcn_mfma_f32_16x16x32_bf16(b1, afrag[tt], acc2, 0, 0, 0);
            }
            select32(acc1, acc2, t * KPT + half * 32);
        }
        if (more) {
            *(short8*)&kst[cur ^ 1][d0] = nA;
            *(short8*)&kst[cur ^ 1][d1] = nB;
        }
        __syncthreads();
        cur ^= 1;
    }

    // Final flush + writeout (quad-orientation; pool sorted desc).
#pragma unroll
    for (int r = 0; r < 4; ++r) {
        const int cc = __shfl(cnt, quad * 4 + r);
        sortmergeU(pk0[r], pk1[r], cc, &bq[wave * 16 + quad * 4 + r][0], l16);
        const size_t base = ((size_t)(q0 + quad * 4 + r) * NSPLIT + split) * TOPK_N;
        cand[base + l16]      = pk0[r];
        cand[base + 16 + l16] = pk1[r];
    }
}

// ---------------------------------------------------------------------------
// Kernel C: narrow-then-rescore.  ROUND 14 recombination of verified parts:
// r12's hybrid 1-elem sort-512 (cheap; j<=32 intra-wave shfl, j in
// {64,128,256} via LDS) + r13's NARROW=64 (passed absmax 0.0; margin:
// 32nd->64th approx gap ~1.5 >> bf16+trunc error ~0.11) + r13's zero-barrier
// wave-0 sort-64.  fp32 rescore uses the SACRED SEQUENTIAL fmaf chain
// (bitwise-matches np reference; do NOT reassociate — round-9 failure).
// One block (512 threads) per query.
// ---------------------------------------------------------------------------
__global__ __launch_bounds__(512) void rescore_gather_kernel(
    const float* __restrict__ qg, const float* __restrict__ keys,
    const float* __restrict__ values, const unsigned* __restrict__ cand,
    float* __restrict__ out)
{
    __shared__ float    qrow[DKDIM];
    __shared__ unsigned spk[NCAND];
    __shared__ int      spn[NCAND];
    __shared__ int      ssi[TOPK_N];
    const int bt  = blockIdx.x;
    const int tid = threadIdx.x;

    if (tid < DKDIM) qrow[tid] = qg[(size_t)bt * DKDIM + tid];

    // Element (pk, n) lives in registers; rank == tid after the sort.
    unsigned pk = cand[(size_t)bt * NCAND + tid];
    int      n  = (tid >> 5) * KPS + (int)(4095u - (pk & 0xFFFu));

    // Hybrid bitonic sort-512, descending by pk (tie -> lower n).
    for (int k = 2; k <= NCAND; k <<= 1) {
        for (int j = k >> 1; j > 0; j >>= 1) {
            unsigned opk; int on;
            if (j >= 64) {                      // cross-wave: via LDS
                __syncthreads();
                spk[tid] = pk; spn[tid] = n;
                __syncthreads();
                opk = spk[tid ^ j]; on = spn[tid ^ j];
            } else {                            // intra-wave: register shfl
                opk = (unsigned)__shfl_xor((int)pk, j);
                on  = __shfl_xor(n, j);
            }
            const bool dir  = ((tid & k) == 0);
            const bool mineFirst = (pk > opk) || (pk == opk && n < on);
            const bool keep = (((tid & j) == 0) == (mineFirst == dir));
            if (!keep) { pk = opk; n = on; }
        }
    }
    __syncthreads();    // qrow visible; sort done

    // Exact fp32 rescore of ranks 0..NARROW-1: sequential fmaf over d=0..127.
    float sc = -FLT_MAX;
    if (tid < NARROW) {
        const float4* krow = (const float4*)(keys + (size_t)n * DKDIM);
        float s = 0.f;
#pragma unroll
        for (int d4 = 0; d4 < DKDIM / 4; ++d4) {
            const float4 k4 = krow[d4];
            const float4 q4 = *(const float4*)&qrow[4 * d4];
            s = fmaf(q4.x, k4.x, s);
            s = fmaf(q4.y, k4.y, s);
            s = fmaf(q4.z, k4.z, s);
            s = fmaf(q4.w, k4.w, s);
        }
        sc = s;
    }

    // Exact bitonic sort-64 (desc, tie -> lower idx): entirely within wave 0
    // (threads 0..63), pure shfl, zero barriers.
    if (tid < 64) {
        for (int k = 2; k <= NARROW; k <<= 1) {
            for (int j = k >> 1; j > 0; j >>= 1) {
                const float of = __shfl_xor(sc, j);
                const int   on = __shfl_xor(n, j);
                const bool dir  = ((tid & k) == 0);
                const bool mineFirst = (sc > of) || (sc == of && n < on);
                const bool keep = (((tid & j) == 0) == (mineFirst == dir));
                if (!keep) { sc = of; n = on; }
            }
        }
        if (tid < TOPK_N) ssi[tid] = n;
    }
    __syncthreads();

    // Gather top-32 K and V rows.
    const int lane = tid & 31;
    const int rb   = tid >> 5;          // [0, 16)
#pragma unroll
    for (int r = 0; r < 2; ++r) {
        const int row = rb + 16 * r;
        const int nn  = ssi[row];
        const float4 kv = *(const float4*)(keys   + (size_t)nn * DKDIM + 4 * lane);
        const float4 vv = *(const float4*)(values + (size_t)nn * DVDIM + 4 * lane);
        const size_t ob = ((size_t)bt * TOPK_N + row) * DKDIM + 4 * lane;
        *(float4*)(out + ob)        = kv;
        *(float4*)(out + NOUT + ob) = vv;
    }
}

extern "C" void kernel_launch(void* const* d_in, const int* in_sizes, int n_in,
                              void* d_out, int out_size, void* d_ws, size_t ws_size,
                              hipStream_t stream)
{
    const float* q      = (const float*)d_in[0];
    const float* keys   = (const float*)d_in[1];
    const float* values = (const float*)d_in[2];
    float* out = (float*)d_out;

    unsigned short* qbf = (unsigned short*)d_ws;                               // 1 MB
    unsigned short* kbf = (unsigned short*)((char*)d_ws + (1u << 20));         // 16 MB
    unsigned* cand = (unsigned*)((char*)d_ws + (17u << 20));                   // 8 MB

    const int cvt_groups = (NQ + NKEYS) * DKDIM / 8;
    convert_kernel<<<(cvt_groups + 255) / 256, 256, 0, stream>>>(q, keys, qbf, kbf);
    score_select_kernel<<<dim3(NQ / BQ, NSPLIT), 512, 0, stream>>>(qbf, kbf, cand);
    rescore_gather_kernel<<<NQ, 512, 0, stream>>>(q, keys, values, cand, out);
}